// Round 6
// baseline (2442.758 us; speedup 1.0000x reference)
//
#include <hip/hip_runtime.h>

#define NC 100352       // N*C = 196*512
typedef unsigned long long ull;

// ---------------------------------------------------------------------------
// Transpose 512x512 weight matrices: Wt[k][c] = W[c][k].
// Wt buffers have 513 rows; row 512 is a prefetch pad (read, never used).
// ---------------------------------------------------------------------------
__global__ __launch_bounds__(256) void transpose_w(
    const float* __restrict__ W0, const float* __restrict__ W1,
    const float* __restrict__ W2, const float* __restrict__ W3,
    float* __restrict__ T0, float* __restrict__ T1,
    float* __restrict__ T2, float* __restrict__ T3)
{
    const int m = blockIdx.z;
    const float* W = (m == 0) ? W0 : (m == 1) ? W1 : (m == 2) ? W2 : W3;
    float* T = (m == 0) ? T0 : (m == 1) ? T1 : (m == 2) ? T2 : T3;
    __shared__ float t[32][33];
    const int bx = blockIdx.x * 32, by = blockIdx.y * 32;
    const int lx = threadIdx.x & 31, ly = threadIdx.x >> 5;
#pragma unroll
    for (int j = 0; j < 32; j += 8)
        t[ly + j][lx] = W[(size_t)(by + ly + j) * 512 + bx + lx];
    __syncthreads();
#pragma unroll
    for (int j = 0; j < 32; j += 8)
        T[(size_t)(bx + ly + j) * 512 + by + lx] = t[lx][ly + j];
}

// ---------------------------------------------------------------------------
// GEMM with wave-uniform B: C[25088,512] = A @ W^T (+bias), W as Wt[k][c].
// Block: 256 rows x 128 cols, 4 waves. Each wave: all 256 rows (4 rows/lane,
// one ds_read_b128 per k) x a 32-col slice whose B values are WAVE-UNIFORM
// (readfirstlane'd base -> scalar loads, no LDS, no VALU). Per wave per k:
// 128 FMA (256 VALU-cy) vs 12 LDS-cy -> FMA-bound even at 4 blocks/CU.
// A-tile LDS double-buffered, BK=16, one barrier per tile.
// Accumulation: k ascending, sequential fmaf per output -> bit-identical to
// the validated rounds 1-5 (absmax 0.0). NMAT=3 packs Q/K/V.
// Grid XCD-swizzled: the 4*NMAT blocks sharing an A row-panel -> same XCD L2.
// ---------------------------------------------------------------------------
template <int NMAT, bool BIAS>
__global__ __launch_bounds__(256) void gemm_wu(
    const float* __restrict__ A,
    const float* __restrict__ Wt0, const float* __restrict__ Wt1,
    const float* __restrict__ Wt2, const float* __restrict__ bias,
    float* __restrict__ C0, float* __restrict__ C1, float* __restrict__ C2)
{
    __shared__ float As[2][16][260];   // 33,280 B; [buf][k][row], 2-way writes

    const int chunk = (NMAT * 392) >> 3;
    const int w = ((int)blockIdx.x & 7) * chunk + ((int)blockIdx.x >> 3);
    const int rp = w / (4 * NMAT);
    const int rem = w - rp * (4 * NMAT);
    const int br = rem >> 2;
    const int cb = rem & 3;

    const float* Wt = (NMAT == 1 || br == 0) ? Wt0 : (br == 1 ? Wt1 : Wt2);
    float* Cb = (NMAT == 1 || br == 0) ? C0 : (br == 1 ? C1 : C2);

    const int tid = threadIdx.x;
    const int lane = tid & 63;
    const int r0 = tid >> 2;          // 0..63 staging row base
    const int kq = (tid & 3) << 2;    // 0,4,8,12 staging k offset

    // Wave-uniform B column base (provably uniform via readfirstlane)
    const int colu = __builtin_amdgcn_readfirstlane(cb * 128 + (tid >> 6) * 32);
    const float* __restrict__ Wu = Wt + colu;

    const float* Ap = A + (size_t)(rp * 256 + r0) * 512 + kq;

    float acc[4][32] = {};
    float4 st[4];

    auto LOAD = [&](int t) {
#pragma unroll
        for (int s = 0; s < 4; ++s)
            st[s] = *(const float4*)(Ap + (size_t)(s * 64) * 512 + t * 16);
    };
    auto STORE = [&](int b) {
#pragma unroll
        for (int s = 0; s < 4; ++s) {
            As[b][kq + 0][r0 + s * 64] = st[s].x;
            As[b][kq + 1][r0 + s * 64] = st[s].y;
            As[b][kq + 2][r0 + s * 64] = st[s].z;
            As[b][kq + 3][r0 + s * 64] = st[s].w;
        }
    };
    auto COMP = [&](int b, int t) {
        const float* wk = Wu + (size_t)t * 16 * 512;
        float4 p[8], nx[8];
#pragma unroll
        for (int g = 0; g < 8; ++g) p[g] = *(const float4*)(wk + g * 4);
#pragma unroll
        for (int k = 0; k < 16; ++k) {
            const float* wn = wk + (size_t)(k + 1) * 512;  // t=31,k=15 -> pad row
#pragma unroll
            for (int g = 0; g < 8; ++g) nx[g] = *(const float4*)(wn + g * 4);
            float av[4];
            *(float4*)&av[0] = *(const float4*)&As[b][k][lane * 4];
#pragma unroll
            for (int i = 0; i < 4; ++i)
#pragma unroll
                for (int g = 0; g < 8; ++g) {
                    acc[i][g * 4 + 0] = fmaf(av[i], p[g].x, acc[i][g * 4 + 0]);
                    acc[i][g * 4 + 1] = fmaf(av[i], p[g].y, acc[i][g * 4 + 1]);
                    acc[i][g * 4 + 2] = fmaf(av[i], p[g].z, acc[i][g * 4 + 2]);
                    acc[i][g * 4 + 3] = fmaf(av[i], p[g].w, acc[i][g * 4 + 3]);
                }
#pragma unroll
            for (int g = 0; g < 8; ++g) p[g] = nx[g];
        }
    };

    LOAD(0);
    STORE(0);
    __syncthreads();
    int cur = 0;
    for (int t = 0; t < 32; ++t) {
        if (t + 1 < 32) LOAD(t + 1);
        COMP(cur, t);
        if (t + 1 < 32) STORE(cur ^ 1);
        __syncthreads();
        cur ^= 1;
    }

    // C write: lane owns rows 4*lane..4*lane+3; wave owns 32-col slice.
    const int rowb = rp * 256 + lane * 4;
    const int colb = cb * 128 + (tid >> 6) * 32;
#pragma unroll
    for (int i = 0; i < 4; ++i)
#pragma unroll
        for (int g = 0; g < 8; ++g) {
            float4 o;
            o.x = acc[i][g * 4 + 0];
            o.y = acc[i][g * 4 + 1];
            o.z = acc[i][g * 4 + 2];
            o.w = acc[i][g * 4 + 3];
            if (BIAS) {
                o.x += bias[colb + g * 4 + 0];
                o.y += bias[colb + g * 4 + 1];
                o.z += bias[colb + g * 4 + 2];
                o.w += bias[colb + g * 4 + 3];
            }
            *(float4*)&Cb[(size_t)(rowb + i) * 512 + colb + g * 4] = o;
        }
}

// ---------------------------------------------------------------------------
// LIF over 128 steps for Q/K/V (one dispatch, br = branch), emitting bitmasks.
// Mask layout: M[br*200704 + t*1568 + h*196 + n], bit = lane = d within head.
// ---------------------------------------------------------------------------
__global__ __launch_bounds__(256) void lif_mask3(
    const float* __restrict__ U0, const float* __restrict__ U1,
    const float* __restrict__ U2,
    const float* __restrict__ wq, const float* __restrict__ wk,
    const float* __restrict__ wv, ull* __restrict__ M)
{
    const int br = blockIdx.x / 392;
    const int blk = blockIdx.x - br * 392;
    const int i = blk * 256 + threadIdx.x;
    const float* U = (br == 0) ? U0 : (br == 1 ? U1 : U2);
    const float wv_ = (br == 0) ? wq[0] : (br == 1 ? wk[0] : wv[0]);
    const float sg = 1.0f / (1.0f + expf(-wv_));
    ull* Mw = M + (size_t)br * 200704 + ((i >> 6) & 7) * 196 + (i >> 9);
    float v = 0.0f;
    for (int t = 0; t < 128; ++t) {
        const float x = U[(size_t)t * NC + i];
        const float h = __fadd_rn(v, __fmul_rn(__fsub_rn(x, v), sg));
        const bool sp = (h >= 1.0f);
        const ull m = __ballot(sp);
        if ((threadIdx.x & 63) == 0) Mw[(size_t)t * 1568] = m;
        v = sp ? 0.0f : h;
    }
}

// ---------------------------------------------------------------------------
// proj LIF: float spikes out.
// ---------------------------------------------------------------------------
__global__ __launch_bounds__(256) void lif_out(const float* __restrict__ U,
                                               const float* __restrict__ wp,
                                               float* __restrict__ out)
{
    const int i = blockIdx.x * 256 + threadIdx.x;
    const float sg = 1.0f / (1.0f + expf(-wp[0]));
    float v = 0.0f;
    for (int t = 0; t < 128; ++t) {
        const float x = U[(size_t)t * NC + i];
        const float h = __fadd_rn(v, __fmul_rn(__fsub_rn(x, v), sg));
        const bool sp = (h >= 1.0f);
        out[(size_t)t * NC + i] = sp ? 1.0f : 0.0f;
        v = sp ? 0.0f : h;
    }
}

// ---------------------------------------------------------------------------
// Fused attention + attn_lif (validated rounds 3-5, unchanged).
// ---------------------------------------------------------------------------
__global__ __launch_bounds__(256) void attn_fused(const ull* __restrict__ Qm,
                                                  const ull* __restrict__ Km,
                                                  const ull* __restrict__ Vm,
                                                  const float* __restrict__ wa,
                                                  float* __restrict__ Y)
{
    const int b = blockIdx.x >> 3;
    const int h = blockIdx.x & 7;
    const int tid = threadIdx.x;
    const int w = tid >> 6;
    const int lane = tid & 63;

    __shared__ ull qrow[256], krow[256], vrow[256];
    __shared__ ull kcol[64][5], vcol[64][5];
    __shared__ ushort G[64][64];
    __shared__ float vstate[196][64];
    __shared__ ull sbm[208];

    const float sg = 1.0f / (1.0f + expf(-wa[0]));

    for (int t = 0; t < 4; ++t) {
        const int tb = t * 32 + b;
        const size_t mb = (size_t)tb * 1568 + (size_t)h * 196;
        if (tid < 196) {
            qrow[tid] = Qm[mb + tid];
            krow[tid] = Km[mb + tid];
            vrow[tid] = Vm[mb + tid];
        } else {
            qrow[tid] = 0; krow[tid] = 0; vrow[tid] = 0;
        }
        __syncthreads();

        {
            ull kc = 0, vc = 0;
#pragma unroll 8
            for (int m = 0; m < 64; ++m) {
                kc |= ((krow[w * 64 + m] >> lane) & 1ull) << m;
                vc |= ((vrow[w * 64 + m] >> lane) & 1ull) << m;
            }
            kcol[lane][w] = kc; vcol[lane][w] = vc;
        }
        __syncthreads();

        for (int p = tid; p < 4096; p += 256) {
            const int d1 = p >> 6, d2 = p & 63;
            const int g = __popcll(kcol[d1][0] & vcol[d2][0]) +
                          __popcll(kcol[d1][1] & vcol[d2][1]) +
                          __popcll(kcol[d1][2] & vcol[d2][2]) +
                          __popcll(kcol[d1][3] & vcol[d2][3]);
            G[d1][d2] = (ushort)g;
        }
        __syncthreads();

        {
            int r = 49 * w;
            const int rend = r + 49;
            for (; r + 1 < rend; r += 2) {
                const ull q0 = qrow[r], q1 = qrow[r + 1];
                const uint a0 = (uint)q0, a1 = (uint)(q0 >> 32);
                const uint b0 = (uint)q1, b1 = (uint)(q1 >> 32);
                uint s0 = 0, s1 = 0;
#pragma unroll
                for (int d = 0; d < 32; ++d) {
                    const uint g = G[d][lane];
                    s0 += ((a0 >> d) & 1u) * g;
                    s1 += ((b0 >> d) & 1u) * g;
                }
#pragma unroll
                for (int d = 0; d < 32; ++d) {
                    const uint g = G[32 + d][lane];
                    s0 += ((a1 >> d) & 1u) * g;
                    s1 += ((b1 >> d) & 1u) * g;
                }
                const float y0 = (float)s0 * 0.125f;
                const float v0 = t ? vstate[r][lane] : 0.0f;
                const float h0 = __fadd_rn(v0, __fmul_rn(__fsub_rn(y0, v0), sg));
                const bool sp0 = h0 >= 1.0f;
                vstate[r][lane] = sp0 ? 0.0f : h0;
                const ull m0 = __ballot(sp0);
                const float y1 = (float)s1 * 0.125f;
                const float v1 = t ? vstate[r + 1][lane] : 0.0f;
                const float h1 = __fadd_rn(v1, __fmul_rn(__fsub_rn(y1, v1), sg));
                const bool sp1 = h1 >= 1.0f;
                vstate[r + 1][lane] = sp1 ? 0.0f : h1;
                const ull m1 = __ballot(sp1);
                if (lane == 0) { sbm[r] = m0; sbm[r + 1] = m1; }
            }
            {
                const ull q0 = qrow[r];
                const uint a0 = (uint)q0, a1 = (uint)(q0 >> 32);
                uint s0 = 0;
#pragma unroll
                for (int d = 0; d < 32; ++d) s0 += ((a0 >> d) & 1u) * (uint)G[d][lane];
#pragma unroll
                for (int d = 0; d < 32; ++d) s0 += ((a1 >> d) & 1u) * (uint)G[32 + d][lane];
                const float y0 = (float)s0 * 0.125f;
                const float v0 = t ? vstate[r][lane] : 0.0f;
                const float h0 = __fadd_rn(v0, __fmul_rn(__fsub_rn(y0, v0), sg));
                const bool sp0 = h0 >= 1.0f;
                vstate[r][lane] = sp0 ? 0.0f : h0;
                const ull m0 = __ballot(sp0);
                if (lane == 0) sbm[r] = m0;
            }
        }
        __syncthreads();

        const size_t yb = (size_t)tb * NC + (size_t)h * 12544;
        for (int f = tid; f < 12544; f += 256) {
            const int e = f / 196;
            const int r2 = f - e * 196;
            Y[yb + f] = ((sbm[r2] >> e) & 1ull) ? 1.0f : 0.0f;
        }
        __syncthreads();
    }
}

// ---------------------------------------------------------------------------
// Workspace (163,160,064 B):
//   u0/u1/u2 : fp32 [128][196][512] 51,380,224 B each
//   Qm/Km/Vm : [128][8][196] ull, 1,605,632 B each
//   Wt q/k/v/p : fp32 [513][512] (row 512 = prefetch pad), 1,050,624 B each
// Aliases: ySc = u0 (dead after lif_mask3); proj-u = u1 (dead after attn).
// ---------------------------------------------------------------------------
extern "C" void kernel_launch(void* const* d_in, const int* in_sizes, int n_in,
                              void* d_out, int out_size, void* d_ws, size_t ws_size,
                              hipStream_t stream) {
    const float* x  = (const float*)d_in[0];
    const float* Wq = (const float*)d_in[1];
    const float* Wk = (const float*)d_in[2];
    const float* Wv = (const float*)d_in[3];
    const float* Wp = (const float*)d_in[4];
    const float* bp = (const float*)d_in[5];
    const float* wq = (const float*)d_in[6];
    const float* wk = (const float*)d_in[7];
    const float* wv = (const float*)d_in[8];
    const float* wa = (const float*)d_in[9];
    const float* wp = (const float*)d_in[10];
    float* out = (float*)d_out;

    char* ws = (char*)d_ws;
    float* u0 = (float*)ws;
    float* u1 = (float*)(ws + (size_t)51380224);
    float* u2 = (float*)(ws + (size_t)2 * 51380224);
    ull* Qm   = (ull*)(ws + (size_t)3 * 51380224);
    ull* Km   = Qm + 200704;
    ull* Vm   = Km + 200704;
    float* Wtq = (float*)(ws + (size_t)3 * 51380224 + (size_t)3 * 1605632);
    float* Wtk = Wtq + 513 * 512;
    float* Wtv = Wtk + 513 * 512;
    float* Wtp = Wtv + 513 * 512;
    float* ySc = u0;   // attn output aliases u0
    float* up  = u1;   // proj GEMM output aliases u1

    // Weight transposes (Wt[k][c])
    transpose_w<<<dim3(16, 16, 4), 256, 0, stream>>>(Wq, Wk, Wv, Wp,
                                                     Wtq, Wtk, Wtv, Wtp);

    // Q/K/V GEMMs in one dispatch (wave-uniform-B kernel)
    gemm_wu<3, false><<<1176, 256, 0, stream>>>(x, Wtq, Wtk, Wtv, nullptr,
                                                u0, u1, u2);
    // LIF -> spike bitmasks
    lif_mask3<<<1176, 256, 0, stream>>>(u0, u1, u2, wq, wk, wv, Qm);

    // Attention + attn_lif -> scrambled float spikes
    attn_fused<<<256, 256, 0, stream>>>(Qm, Km, Vm, wa, ySc);

    // Projection + bias
    gemm_wu<1, true><<<392, 256, 0, stream>>>(ySc, Wtp, nullptr, nullptr, bp,
                                              up, nullptr, nullptr);
    // proj LIF -> output spikes
    lif_out<<<392, 256, 0, stream>>>(up, wp, out);
}

// Round 7
// 1081.792 us; speedup vs baseline: 2.2581x; 2.2581x over previous
//
#include <hip/hip_runtime.h>

#define NC 100352       // N*C = 196*512
typedef unsigned long long ull;
typedef float (*tile16)[132];

// ---------------------------------------------------------------------------
// GEMM: C[25088,512] = A[25088,512] @ W[512,512]^T (+bias).
// Round-2 core (validated 202 us/GEMM): 128x128 tile, BK=16, 256 threads,
// 8x8 microtile split 4+4 at +64 -> conflict-free b128 reads, k-ascending
// sequential fmaf per output (bit-identical, absmax 0.0 rounds 1-6).
// New here: double-buffered LDS (ONE barrier per BK step) and NMAT=3 packing
// Q/K/V into a single 2352-block dispatch, XCD-swizzled so the 12 blocks
// sharing an A row-panel co-reside on one XCD's L2.
// ---------------------------------------------------------------------------
template <int NMAT, bool BIAS>
__global__ __launch_bounds__(256) void gemm_nt(
    const float* __restrict__ A,
    const float* __restrict__ W0, const float* __restrict__ W1,
    const float* __restrict__ W2, const float* __restrict__ bias,
    float* __restrict__ C0, float* __restrict__ C1, float* __restrict__ C2)
{
    __shared__ float As[2][16][132];   // 16,896 B
    __shared__ float Bs[2][16][132];   // 16,896 B  (total 33,792)

    const int chunk = (NMAT * 784) >> 3;
    const int w = ((int)blockIdx.x & 7) * chunk + ((int)blockIdx.x >> 3);
    const int rp = w / (4 * NMAT);                 // row panel 0..195
    const int rem = w - rp * (4 * NMAT);
    const int br = rem >> 2;
    const int cb = rem & 3;

    const float* Wb = (NMAT == 1 || br == 0) ? W0 : (br == 1 ? W1 : W2);
    float* Cb = (NMAT == 1 || br == 0) ? C0 : (br == 1 ? C1 : C2);

    const int tid = threadIdx.x;
    const int r0 = tid >> 2;          // 0..63 : staging row
    const int kq = (tid & 3) << 2;    // 0,4,8,12 : staging k offset (float4)
    const int rg = (tid >> 4) << 2;   // compute row base
    const int cg = (tid & 15) << 2;   // compute col base

    const float* A0 = A + (size_t)(rp * 128 + r0) * 512 + kq;
    const float* A1 = A0 + (size_t)64 * 512;
    const float* B0 = Wb + (size_t)(cb * 128 + r0) * 512 + kq;
    const float* B1 = B0 + (size_t)64 * 512;

    float acc[8][8] = {};
    float4 sa0, sa1, sb0, sb1;

    auto LOAD = [&](int k0) {
        sa0 = *(const float4*)(A0 + k0);
        sa1 = *(const float4*)(A1 + k0);
        sb0 = *(const float4*)(B0 + k0);
        sb1 = *(const float4*)(B1 + k0);
    };
    auto STORE = [&](int b) {
        As[b][kq + 0][r0] = sa0.x; As[b][kq + 1][r0] = sa0.y;
        As[b][kq + 2][r0] = sa0.z; As[b][kq + 3][r0] = sa0.w;
        As[b][kq + 0][r0 + 64] = sa1.x; As[b][kq + 1][r0 + 64] = sa1.y;
        As[b][kq + 2][r0 + 64] = sa1.z; As[b][kq + 3][r0 + 64] = sa1.w;
        Bs[b][kq + 0][r0] = sb0.x; Bs[b][kq + 1][r0] = sb0.y;
        Bs[b][kq + 2][r0] = sb0.z; Bs[b][kq + 3][r0] = sb0.w;
        Bs[b][kq + 0][r0 + 64] = sb1.x; Bs[b][kq + 1][r0 + 64] = sb1.y;
        Bs[b][kq + 2][r0 + 64] = sb1.z; Bs[b][kq + 3][r0 + 64] = sb1.w;
    };
    auto COMP = [&](int b) {
#pragma unroll
        for (int k = 0; k < 16; ++k) {
            float av[8], bv[8];
            *(float4*)&av[0] = *(const float4*)&As[b][k][rg];
            *(float4*)&av[4] = *(const float4*)&As[b][k][rg + 64];
            *(float4*)&bv[0] = *(const float4*)&Bs[b][k][cg];
            *(float4*)&bv[4] = *(const float4*)&Bs[b][k][cg + 64];
#pragma unroll
            for (int i = 0; i < 8; ++i)
#pragma unroll
                for (int j = 0; j < 8; ++j)
                    acc[i][j] = fmaf(av[i], bv[j], acc[i][j]);
        }
    };

    LOAD(0);
    STORE(0);
    __syncthreads();
    int cur = 0;
    for (int k0 = 0; k0 < 512; k0 += 16) {
        if (k0 + 16 < 512) LOAD(k0 + 16);
        COMP(cur);
        if (k0 + 16 < 512) STORE(cur ^ 1);
        __syncthreads();
        cur ^= 1;
    }

#pragma unroll
    for (int ih = 0; ih < 2; ++ih)
#pragma unroll
        for (int i = 0; i < 4; ++i) {
            const int row = rp * 128 + rg + i + ih * 64;
#pragma unroll
            for (int jh = 0; jh < 2; ++jh) {
                const int col = cb * 128 + cg + jh * 64;
                float4 o;
                o.x = acc[ih * 4 + i][jh * 4 + 0];
                o.y = acc[ih * 4 + i][jh * 4 + 1];
                o.z = acc[ih * 4 + i][jh * 4 + 2];
                o.w = acc[ih * 4 + i][jh * 4 + 3];
                if (BIAS) {
                    o.x += bias[col + 0]; o.y += bias[col + 1];
                    o.z += bias[col + 2]; o.w += bias[col + 3];
                }
                *(float4*)&Cb[(size_t)row * 512 + col] = o;
            }
        }
}

// ---------------------------------------------------------------------------
// LIF over 128 steps for Q/K/V (one dispatch, br = branch), emitting bitmasks.
// Mask layout: M[br*200704 + t*1568 + h*196 + n], bit = lane = d within head.
// ---------------------------------------------------------------------------
__global__ __launch_bounds__(256) void lif_mask3(
    const float* __restrict__ U0, const float* __restrict__ U1,
    const float* __restrict__ U2,
    const float* __restrict__ wq, const float* __restrict__ wk,
    const float* __restrict__ wv, ull* __restrict__ M)
{
    const int br = blockIdx.x / 392;
    const int blk = blockIdx.x - br * 392;
    const int i = blk * 256 + threadIdx.x;
    const float* U = (br == 0) ? U0 : (br == 1 ? U1 : U2);
    const float wv_ = (br == 0) ? wq[0] : (br == 1 ? wk[0] : wv[0]);
    const float sg = 1.0f / (1.0f + expf(-wv_));
    ull* Mw = M + (size_t)br * 200704 + ((i >> 6) & 7) * 196 + (i >> 9);
    float v = 0.0f;
    for (int t = 0; t < 128; ++t) {
        const float x = U[(size_t)t * NC + i];
        const float h = __fadd_rn(v, __fmul_rn(__fsub_rn(x, v), sg));
        const bool sp = (h >= 1.0f);
        const ull m = __ballot(sp);
        if ((threadIdx.x & 63) == 0) Mw[(size_t)t * 1568] = m;
        v = sp ? 0.0f : h;
    }
}

// ---------------------------------------------------------------------------
// proj LIF: float spikes out.
// ---------------------------------------------------------------------------
__global__ __launch_bounds__(256) void lif_out(const float* __restrict__ U,
                                               const float* __restrict__ wp,
                                               float* __restrict__ out)
{
    const int i = blockIdx.x * 256 + threadIdx.x;
    const float sg = 1.0f / (1.0f + expf(-wp[0]));
    float v = 0.0f;
    for (int t = 0; t < 128; ++t) {
        const float x = U[(size_t)t * NC + i];
        const float h = __fadd_rn(v, __fmul_rn(__fsub_rn(x, v), sg));
        const bool sp = (h >= 1.0f);
        out[(size_t)t * NC + i] = sp ? 1.0f : 0.0f;
        v = sp ? 0.0f : h;
    }
}

// ---------------------------------------------------------------------------
// Fused attention + attn_lif (validated rounds 3-6, unchanged).
// ---------------------------------------------------------------------------
__global__ __launch_bounds__(256) void attn_fused(const ull* __restrict__ Qm,
                                                  const ull* __restrict__ Km,
                                                  const ull* __restrict__ Vm,
                                                  const float* __restrict__ wa,
                                                  float* __restrict__ Y)
{
    const int b = blockIdx.x >> 3;
    const int h = blockIdx.x & 7;
    const int tid = threadIdx.x;
    const int w = tid >> 6;
    const int lane = tid & 63;

    __shared__ ull qrow[256], krow[256], vrow[256];
    __shared__ ull kcol[64][5], vcol[64][5];
    __shared__ ushort G[64][64];
    __shared__ float vstate[196][64];
    __shared__ ull sbm[208];

    const float sg = 1.0f / (1.0f + expf(-wa[0]));

    for (int t = 0; t < 4; ++t) {
        const int tb = t * 32 + b;
        const size_t mb = (size_t)tb * 1568 + (size_t)h * 196;
        if (tid < 196) {
            qrow[tid] = Qm[mb + tid];
            krow[tid] = Km[mb + tid];
            vrow[tid] = Vm[mb + tid];
        } else {
            qrow[tid] = 0; krow[tid] = 0; vrow[tid] = 0;
        }
        __syncthreads();

        {
            ull kc = 0, vc = 0;
#pragma unroll 8
            for (int m = 0; m < 64; ++m) {
                kc |= ((krow[w * 64 + m] >> lane) & 1ull) << m;
                vc |= ((vrow[w * 64 + m] >> lane) & 1ull) << m;
            }
            kcol[lane][w] = kc; vcol[lane][w] = vc;
        }
        __syncthreads();

        for (int p = tid; p < 4096; p += 256) {
            const int d1 = p >> 6, d2 = p & 63;
            const int g = __popcll(kcol[d1][0] & vcol[d2][0]) +
                          __popcll(kcol[d1][1] & vcol[d2][1]) +
                          __popcll(kcol[d1][2] & vcol[d2][2]) +
                          __popcll(kcol[d1][3] & vcol[d2][3]);
            G[d1][d2] = (ushort)g;
        }
        __syncthreads();

        {
            int r = 49 * w;
            const int rend = r + 49;
            for (; r + 1 < rend; r += 2) {
                const ull q0 = qrow[r], q1 = qrow[r + 1];
                const uint a0 = (uint)q0, a1 = (uint)(q0 >> 32);
                const uint b0 = (uint)q1, b1 = (uint)(q1 >> 32);
                uint s0 = 0, s1 = 0;
#pragma unroll
                for (int d = 0; d < 32; ++d) {
                    const uint g = G[d][lane];
                    s0 += ((a0 >> d) & 1u) * g;
                    s1 += ((b0 >> d) & 1u) * g;
                }
#pragma unroll
                for (int d = 0; d < 32; ++d) {
                    const uint g = G[32 + d][lane];
                    s0 += ((a1 >> d) & 1u) * g;
                    s1 += ((b1 >> d) & 1u) * g;
                }
                const float y0 = (float)s0 * 0.125f;
                const float v0 = t ? vstate[r][lane] : 0.0f;
                const float h0 = __fadd_rn(v0, __fmul_rn(__fsub_rn(y0, v0), sg));
                const bool sp0 = h0 >= 1.0f;
                vstate[r][lane] = sp0 ? 0.0f : h0;
                const ull m0 = __ballot(sp0);
                const float y1 = (float)s1 * 0.125f;
                const float v1 = t ? vstate[r + 1][lane] : 0.0f;
                const float h1 = __fadd_rn(v1, __fmul_rn(__fsub_rn(y1, v1), sg));
                const bool sp1 = h1 >= 1.0f;
                vstate[r + 1][lane] = sp1 ? 0.0f : h1;
                const ull m1 = __ballot(sp1);
                if (lane == 0) { sbm[r] = m0; sbm[r + 1] = m1; }
            }
            {
                const ull q0 = qrow[r];
                const uint a0 = (uint)q0, a1 = (uint)(q0 >> 32);
                uint s0 = 0;
#pragma unroll
                for (int d = 0; d < 32; ++d) s0 += ((a0 >> d) & 1u) * (uint)G[d][lane];
#pragma unroll
                for (int d = 0; d < 32; ++d) s0 += ((a1 >> d) & 1u) * (uint)G[32 + d][lane];
                const float y0 = (float)s0 * 0.125f;
                const float v0 = t ? vstate[r][lane] : 0.0f;
                const float h0 = __fadd_rn(v0, __fmul_rn(__fsub_rn(y0, v0), sg));
                const bool sp0 = h0 >= 1.0f;
                vstate[r][lane] = sp0 ? 0.0f : h0;
                const ull m0 = __ballot(sp0);
                if (lane == 0) sbm[r] = m0;
            }
        }
        __syncthreads();

        const size_t yb = (size_t)tb * NC + (size_t)h * 12544;
        for (int f = tid; f < 12544; f += 256) {
            const int e = f / 196;
            const int r2 = f - e * 196;
            Y[yb + f] = ((sbm[r2] >> e) & 1ull) ? 1.0f : 0.0f;
        }
        __syncthreads();
    }
}

// ---------------------------------------------------------------------------
// Workspace (158,957,568 B):
//   u0/u1/u2 : fp32 [128][196][512] 51,380,224 B each
//   Qm/Km/Vm : [128][8][196] ull, 1,605,632 B each
// Aliases: ySc = u0 (dead after lif_mask3); proj-u = u1 (dead after attn).
// ---------------------------------------------------------------------------
extern "C" void kernel_launch(void* const* d_in, const int* in_sizes, int n_in,
                              void* d_out, int out_size, void* d_ws, size_t ws_size,
                              hipStream_t stream) {
    const float* x  = (const float*)d_in[0];
    const float* Wq = (const float*)d_in[1];
    const float* Wk = (const float*)d_in[2];
    const float* Wv = (const float*)d_in[3];
    const float* Wp = (const float*)d_in[4];
    const float* bp = (const float*)d_in[5];
    const float* wq = (const float*)d_in[6];
    const float* wk = (const float*)d_in[7];
    const float* wv = (const float*)d_in[8];
    const float* wa = (const float*)d_in[9];
    const float* wp = (const float*)d_in[10];
    float* out = (float*)d_out;

    char* ws = (char*)d_ws;
    float* u0 = (float*)ws;
    float* u1 = (float*)(ws + (size_t)51380224);
    float* u2 = (float*)(ws + (size_t)2 * 51380224);
    ull* Qm   = (ull*)(ws + (size_t)3 * 51380224);
    ull* Km   = Qm + 200704;
    ull* Vm   = Km + 200704;
    float* ySc = u0;   // attn output aliases u0
    float* up  = u1;   // proj GEMM output aliases u1

    // Q/K/V GEMMs: one merged dispatch, 2352 blocks, XCD-swizzled
    gemm_nt<3, false><<<2352, 256, 0, stream>>>(x, Wq, Wk, Wv, nullptr,
                                                u0, u1, u2);
    // LIF -> spike bitmasks
    lif_mask3<<<1176, 256, 0, stream>>>(u0, u1, u2, wq, wk, wv, Qm);

    // Attention + attn_lif -> scrambled float spikes
    attn_fused<<<256, 256, 0, stream>>>(Qm, Km, Vm, wa, ySc);

    // Projection + bias
    gemm_nt<1, true><<<784, 256, 0, stream>>>(ySc, Wp, nullptr, nullptr, bp,
                                              up, nullptr, nullptr);
    // proj LIF -> output spikes
    lif_out<<<392, 256, 0, stream>>>(up, wp, out);
}

// Round 8
// 816.619 us; speedup vs baseline: 2.9913x; 1.3247x over previous
//
#include <hip/hip_runtime.h>

#define NC 100352       // N*C = 196*512
typedef unsigned long long ull;

// ---------------------------------------------------------------------------
// GEMM: C[25088,512] = A[25088,512] @ W[512,512]^T (+bias).
// EXACT round-2 body (validated 202 us/GEMM, VGPR 72): 128x128 tile, BK=16,
// 256 threads, 8x8 microtile split 4+4 at +64, single-buffered LDS with the
// load->sync->store->sync->comp loop. k-ascending sequential fmaf per output
// -> bit-identical (absmax 0.0, rounds 1-7).
// Only change: NMAT=3 packs Q/K/V into one 2352-block dispatch (7 resident
// blocks/CU instead of 3) with XCD-bijective swizzle so the 12 blocks
// sharing an A row-panel co-reside on one XCD's L2.
// ---------------------------------------------------------------------------
template <int NMAT, bool BIAS>
__global__ __launch_bounds__(256) void gemm_nt(
    const float* __restrict__ A,
    const float* __restrict__ W0, const float* __restrict__ W1,
    const float* __restrict__ W2, const float* __restrict__ bias,
    float* __restrict__ C0, float* __restrict__ C1, float* __restrict__ C2)
{
    __shared__ float As[16][132];
    __shared__ float Bs[16][132];

    const int chunk = (NMAT * 784) >> 3;
    const int w = ((int)blockIdx.x & 7) * chunk + ((int)blockIdx.x >> 3);
    const int rp = w / (4 * NMAT);                 // row panel 0..195
    const int rem = w - rp * (4 * NMAT);
    const int br = rem >> 2;
    const int cb = rem & 3;

    const float* Wb = (NMAT == 1 || br == 0) ? W0 : (br == 1 ? W1 : W2);
    float* Cb = (NMAT == 1 || br == 0) ? C0 : (br == 1 ? C1 : C2);

    const int tid = threadIdx.x;
    const int r0 = tid >> 2;          // 0..63 load row (and +64)
    const int kq = (tid & 3) << 2;    // 0,4,8,12 k-offset for float4 load
    const int rg = (tid >> 4) << 2;   // compute row base
    const int cg = (tid & 15) << 2;   // compute col base

    float acc[8][8] = {};
    const float* A0 = A + (size_t)(rp * 128 + r0) * 512 + kq;
    const float* A1 = A0 + (size_t)64 * 512;
    const float* B0 = Wb + (size_t)(cb * 128 + r0) * 512 + kq;
    const float* B1 = B0 + (size_t)64 * 512;

    for (int k0 = 0; k0 < 512; k0 += 16) {
        const float4 a0 = *(const float4*)(A0 + k0);
        const float4 a1 = *(const float4*)(A1 + k0);
        const float4 b0 = *(const float4*)(B0 + k0);
        const float4 b1 = *(const float4*)(B1 + k0);
        __syncthreads();  // previous iteration's LDS reads done
        As[kq + 0][r0] = a0.x; As[kq + 1][r0] = a0.y; As[kq + 2][r0] = a0.z; As[kq + 3][r0] = a0.w;
        As[kq + 0][r0 + 64] = a1.x; As[kq + 1][r0 + 64] = a1.y; As[kq + 2][r0 + 64] = a1.z; As[kq + 3][r0 + 64] = a1.w;
        Bs[kq + 0][r0] = b0.x; Bs[kq + 1][r0] = b0.y; Bs[kq + 2][r0] = b0.z; Bs[kq + 3][r0] = b0.w;
        Bs[kq + 0][r0 + 64] = b1.x; Bs[kq + 1][r0 + 64] = b1.y; Bs[kq + 2][r0 + 64] = b1.z; Bs[kq + 3][r0 + 64] = b1.w;
        __syncthreads();
#pragma unroll
        for (int k = 0; k < 16; ++k) {
            float av[8], bv[8];
            *(float4*)&av[0] = *(const float4*)&As[k][rg];
            *(float4*)&av[4] = *(const float4*)&As[k][rg + 64];
            *(float4*)&bv[0] = *(const float4*)&Bs[k][cg];
            *(float4*)&bv[4] = *(const float4*)&Bs[k][cg + 64];
#pragma unroll
            for (int i = 0; i < 8; ++i)
#pragma unroll
                for (int j = 0; j < 8; ++j)
                    acc[i][j] = fmaf(av[i], bv[j], acc[i][j]);
        }
    }

#pragma unroll
    for (int ih = 0; ih < 2; ++ih)
#pragma unroll
        for (int i = 0; i < 4; ++i) {
            const int row = rp * 128 + rg + i + ih * 64;
#pragma unroll
            for (int jh = 0; jh < 2; ++jh) {
                const int col = cb * 128 + cg + jh * 64;
                float4 o;
                o.x = acc[ih * 4 + i][jh * 4 + 0];
                o.y = acc[ih * 4 + i][jh * 4 + 1];
                o.z = acc[ih * 4 + i][jh * 4 + 2];
                o.w = acc[ih * 4 + i][jh * 4 + 3];
                if (BIAS) {
                    o.x += bias[col + 0]; o.y += bias[col + 1];
                    o.z += bias[col + 2]; o.w += bias[col + 3];
                }
                *(float4*)&Cb[(size_t)row * 512 + col] = o;
            }
        }
}

// ---------------------------------------------------------------------------
// LIF over 128 steps for Q/K/V (one dispatch, br = branch), emitting bitmasks.
// Mask layout: M[br*200704 + t*1568 + h*196 + n], bit = lane = d within head.
// ---------------------------------------------------------------------------
__global__ __launch_bounds__(256) void lif_mask3(
    const float* __restrict__ U0, const float* __restrict__ U1,
    const float* __restrict__ U2,
    const float* __restrict__ wq, const float* __restrict__ wk,
    const float* __restrict__ wv, ull* __restrict__ M)
{
    const int br = blockIdx.x / 392;
    const int blk = blockIdx.x - br * 392;
    const int i = blk * 256 + threadIdx.x;
    const float* U = (br == 0) ? U0 : (br == 1 ? U1 : U2);
    const float wv_ = (br == 0) ? wq[0] : (br == 1 ? wk[0] : wv[0]);
    const float sg = 1.0f / (1.0f + expf(-wv_));
    ull* Mw = M + (size_t)br * 200704 + ((i >> 6) & 7) * 196 + (i >> 9);
    float v = 0.0f;
    for (int t = 0; t < 128; ++t) {
        const float x = U[(size_t)t * NC + i];
        const float h = __fadd_rn(v, __fmul_rn(__fsub_rn(x, v), sg));
        const bool sp = (h >= 1.0f);
        const ull m = __ballot(sp);
        if ((threadIdx.x & 63) == 0) Mw[(size_t)t * 1568] = m;
        v = sp ? 0.0f : h;
    }
}

// ---------------------------------------------------------------------------
// proj LIF: float spikes out.
// ---------------------------------------------------------------------------
__global__ __launch_bounds__(256) void lif_out(const float* __restrict__ U,
                                               const float* __restrict__ wp,
                                               float* __restrict__ out)
{
    const int i = blockIdx.x * 256 + threadIdx.x;
    const float sg = 1.0f / (1.0f + expf(-wp[0]));
    float v = 0.0f;
    for (int t = 0; t < 128; ++t) {
        const float x = U[(size_t)t * NC + i];
        const float h = __fadd_rn(v, __fmul_rn(__fsub_rn(x, v), sg));
        const bool sp = (h >= 1.0f);
        out[(size_t)t * NC + i] = sp ? 1.0f : 0.0f;
        v = sp ? 0.0f : h;
    }
}

// ---------------------------------------------------------------------------
// Fused attention + attn_lif (validated rounds 3-7, unchanged).
// ---------------------------------------------------------------------------
__global__ __launch_bounds__(256) void attn_fused(const ull* __restrict__ Qm,
                                                  const ull* __restrict__ Km,
                                                  const ull* __restrict__ Vm,
                                                  const float* __restrict__ wa,
                                                  float* __restrict__ Y)
{
    const int b = blockIdx.x >> 3;
    const int h = blockIdx.x & 7;
    const int tid = threadIdx.x;
    const int w = tid >> 6;
    const int lane = tid & 63;

    __shared__ ull qrow[256], krow[256], vrow[256];
    __shared__ ull kcol[64][5], vcol[64][5];
    __shared__ ushort G[64][64];
    __shared__ float vstate[196][64];
    __shared__ ull sbm[208];

    const float sg = 1.0f / (1.0f + expf(-wa[0]));

    for (int t = 0; t < 4; ++t) {
        const int tb = t * 32 + b;
        const size_t mb = (size_t)tb * 1568 + (size_t)h * 196;
        if (tid < 196) {
            qrow[tid] = Qm[mb + tid];
            krow[tid] = Km[mb + tid];
            vrow[tid] = Vm[mb + tid];
        } else {
            qrow[tid] = 0; krow[tid] = 0; vrow[tid] = 0;
        }
        __syncthreads();

        {
            ull kc = 0, vc = 0;
#pragma unroll 8
            for (int m = 0; m < 64; ++m) {
                kc |= ((krow[w * 64 + m] >> lane) & 1ull) << m;
                vc |= ((vrow[w * 64 + m] >> lane) & 1ull) << m;
            }
            kcol[lane][w] = kc; vcol[lane][w] = vc;
        }
        __syncthreads();

        for (int p = tid; p < 4096; p += 256) {
            const int d1 = p >> 6, d2 = p & 63;
            const int g = __popcll(kcol[d1][0] & vcol[d2][0]) +
                          __popcll(kcol[d1][1] & vcol[d2][1]) +
                          __popcll(kcol[d1][2] & vcol[d2][2]) +
                          __popcll(kcol[d1][3] & vcol[d2][3]);
            G[d1][d2] = (ushort)g;
        }
        __syncthreads();

        {
            int r = 49 * w;
            const int rend = r + 49;
            for (; r + 1 < rend; r += 2) {
                const ull q0 = qrow[r], q1 = qrow[r + 1];
                const uint a0 = (uint)q0, a1 = (uint)(q0 >> 32);
                const uint b0 = (uint)q1, b1 = (uint)(q1 >> 32);
                uint s0 = 0, s1 = 0;
#pragma unroll
                for (int d = 0; d < 32; ++d) {
                    const uint g = G[d][lane];
                    s0 += ((a0 >> d) & 1u) * g;
                    s1 += ((b0 >> d) & 1u) * g;
                }
#pragma unroll
                for (int d = 0; d < 32; ++d) {
                    const uint g = G[32 + d][lane];
                    s0 += ((a1 >> d) & 1u) * g;
                    s1 += ((b1 >> d) & 1u) * g;
                }
                const float y0 = (float)s0 * 0.125f;
                const float v0 = t ? vstate[r][lane] : 0.0f;
                const float h0 = __fadd_rn(v0, __fmul_rn(__fsub_rn(y0, v0), sg));
                const bool sp0 = h0 >= 1.0f;
                vstate[r][lane] = sp0 ? 0.0f : h0;
                const ull m0 = __ballot(sp0);
                const float y1 = (float)s1 * 0.125f;
                const float v1 = t ? vstate[r + 1][lane] : 0.0f;
                const float h1 = __fadd_rn(v1, __fmul_rn(__fsub_rn(y1, v1), sg));
                const bool sp1 = h1 >= 1.0f;
                vstate[r + 1][lane] = sp1 ? 0.0f : h1;
                const ull m1 = __ballot(sp1);
                if (lane == 0) { sbm[r] = m0; sbm[r + 1] = m1; }
            }
            {
                const ull q0 = qrow[r];
                const uint a0 = (uint)q0, a1 = (uint)(q0 >> 32);
                uint s0 = 0;
#pragma unroll
                for (int d = 0; d < 32; ++d) s0 += ((a0 >> d) & 1u) * (uint)G[d][lane];
#pragma unroll
                for (int d = 0; d < 32; ++d) s0 += ((a1 >> d) & 1u) * (uint)G[32 + d][lane];
                const float y0 = (float)s0 * 0.125f;
                const float v0 = t ? vstate[r][lane] : 0.0f;
                const float h0 = __fadd_rn(v0, __fmul_rn(__fsub_rn(y0, v0), sg));
                const bool sp0 = h0 >= 1.0f;
                vstate[r][lane] = sp0 ? 0.0f : h0;
                const ull m0 = __ballot(sp0);
                if (lane == 0) sbm[r] = m0;
            }
        }
        __syncthreads();

        const size_t yb = (size_t)tb * NC + (size_t)h * 12544;
        for (int f = tid; f < 12544; f += 256) {
            const int e = f / 196;
            const int r2 = f - e * 196;
            Y[yb + f] = ((sbm[r2] >> e) & 1ull) ? 1.0f : 0.0f;
        }
        __syncthreads();
    }
}

// ---------------------------------------------------------------------------
// Workspace (158,957,568 B):
//   u0/u1/u2 : fp32 [128][196][512] 51,380,224 B each
//   Qm/Km/Vm : [128][8][196] ull, 1,605,632 B each
// Aliases: ySc = u0 (dead after lif_mask3); proj-u = u1 (dead after attn).
// ---------------------------------------------------------------------------
extern "C" void kernel_launch(void* const* d_in, const int* in_sizes, int n_in,
                              void* d_out, int out_size, void* d_ws, size_t ws_size,
                              hipStream_t stream) {
    const float* x  = (const float*)d_in[0];
    const float* Wq = (const float*)d_in[1];
    const float* Wk = (const float*)d_in[2];
    const float* Wv = (const float*)d_in[3];
    const float* Wp = (const float*)d_in[4];
    const float* bp = (const float*)d_in[5];
    const float* wq = (const float*)d_in[6];
    const float* wk = (const float*)d_in[7];
    const float* wv = (const float*)d_in[8];
    const float* wa = (const float*)d_in[9];
    const float* wp = (const float*)d_in[10];
    float* out = (float*)d_out;

    char* ws = (char*)d_ws;
    float* u0 = (float*)ws;
    float* u1 = (float*)(ws + (size_t)51380224);
    float* u2 = (float*)(ws + (size_t)2 * 51380224);
    ull* Qm   = (ull*)(ws + (size_t)3 * 51380224);
    ull* Km   = Qm + 200704;
    ull* Vm   = Km + 200704;
    float* ySc = u0;   // attn output aliases u0
    float* up  = u1;   // proj GEMM output aliases u1

    // Q/K/V GEMMs: one merged dispatch, 2352 blocks, XCD-swizzled,
    // round-2 single-buffer body (low VGPR -> high occupancy)
    gemm_nt<3, false><<<2352, 256, 0, stream>>>(x, Wq, Wk, Wv, nullptr,
                                                u0, u1, u2);
    // LIF -> spike bitmasks
    lif_mask3<<<1176, 256, 0, stream>>>(u0, u1, u2, wq, wk, wv, Qm);

    // Attention + attn_lif -> scrambled float spikes
    attn_fused<<<256, 256, 0, stream>>>(Qm, Km, Vm, wa, ySc);

    // Projection + bias
    gemm_nt<1, true><<<784, 256, 0, stream>>>(ySc, Wp, nullptr, nullptr, bp,
                                              up, nullptr, nullptr);
    // proj LIF -> output spikes
    lif_out<<<392, 256, 0, stream>>>(up, wp, out);
}